// Round 1
// baseline (39.705 us; speedup 1.0000x reference)
//
#include <hip/hip_runtime.h>

typedef __attribute__((ext_vector_type(8))) short bf16x8;
typedef __attribute__((ext_vector_type(4))) float f32x4;

__device__ __forceinline__ unsigned short f2bf(float f){
  union { float f; unsigned int u; } v; v.f = f;
  unsigned int u = v.u;
  return (unsigned short)((u + 0x7FFFu + ((u >> 16) & 1u)) >> 16);  // RNE
}

__device__ __forceinline__ float fast_tanh(float x){
  x = fminf(15.f, fmaxf(-15.f, x));
  float e = __expf(2.f * x);
  return (e - 1.f) / (e + 1.f);
}

// ---------------------------------------------------------------------------
// K0: precompute small tables into ws (floats):
//   [0..1024)    MT[g*32+h] = M[h][g] = sum_c Wk2[h][c]*Wq2[g][c]
//   [1024..1056) u[h]  = sum_c Wk2[h][c]*bq2[c]
//   [1056..1088) r[g]  = sum_c Wq2[g][c]*bk2[c]
//   [1088..1120) wv[h] = sum_c Wv2[h][c]*Wval[c]
//   [1120]       cc = bk2.bq2      [1121] cv = bv2.Wval1
//   ws+1152 floats: Bpack (12288 bf16): layer-1 weights in MFMA B-frag order
//     idx = ((m*2+nt)*4+kc)*512 + lane*8 + e
//     val = bf16( W1_m[(kc*32 + (lane>>4)*8 + e)*32 + nt*16 + (lane&15)] )
// ---------------------------------------------------------------------------
__global__ __launch_bounds__(64) void k0_kernel(
    const float* __restrict__ Wk1, const float* __restrict__ Wq1, const float* __restrict__ Wv1,
    const float* __restrict__ Wk2, const float* __restrict__ bk2,
    const float* __restrict__ Wq2, const float* __restrict__ bq2,
    const float* __restrict__ Wv2, const float* __restrict__ bv2,
    const float* __restrict__ Wval, float* __restrict__ ws)
{
  const int tid = blockIdx.x * 64 + threadIdx.x;  // 0..4095
  if (tid < 1024){
    const int g = tid >> 5, h = tid & 31;
    const float* wk = Wk2 + h * 128;
    const float* wq = Wq2 + g * 128;
    float s = 0.f;
    for (int c = 0; c < 128; c += 4){
      float4 a = *(const float4*)(wk + c);
      float4 bqv = *(const float4*)(wq + c);
      s += a.x*bqv.x + a.y*bqv.y + a.z*bqv.z + a.w*bqv.w;
    }
    ws[tid] = s;                       // MT[g*32+h]
  } else if (tid < 1120){
    const int h = tid - 1024; const int m = h >> 5; const int hh = h & 31;
    const float* W2  = (m == 0) ? Wk2 : ((m == 1) ? Wq2 : Wv2);
    const float* vec = (m == 0) ? bq2 : ((m == 1) ? bk2 : Wval);
    float s = 0.f;
    for (int c = 0; c < 128; c++) s += W2[hh * 128 + c] * vec[c];
    ws[1024 + m * 32 + hh] = s;
  } else if (tid == 1120){
    float s = 0.f; for (int c = 0; c < 128; c++) s += bk2[c] * bq2[c];
    ws[1120] = s;
  } else if (tid == 1121){
    float s = 0.f; for (int c = 0; c < 128; c++) s += bv2[c] * Wval[c];
    ws[1121] = s;
  }
  unsigned short* bp = (unsigned short*)(ws + 1152);
  for (int idx = tid; idx < 12288; idx += 4096){
    const int e  = idx & 7;
    const int l  = (idx >> 3) & 63;
    const int kc = (idx >> 9) & 3;
    const int nt = (idx >> 11) & 1;
    const int m  = idx >> 12;
    const float* W1 = (m == 0) ? Wk1 : ((m == 1) ? Wq1 : Wv1);
    const int krow = kc * 32 + (l >> 4) * 8 + e;
    const int col  = nt * 16 + (l & 15);
    bp[idx] = f2bf(W1[krow * 32 + col]);
  }
}

// ---------------------------------------------------------------------------
// KA: one wave per batch. Layer-1 MLPs via bf16 MFMA, scores via M-table in
// fp32 VALU, shfl softmax, writes alpha (output 1) and ov[] (to ws).
// ---------------------------------------------------------------------------
#define HSTR 20

#define ROWSOFTMAX(sv, aout) { \
    float m_ = sv; \
    m_ = fmaxf(m_, __shfl_xor(m_, 1)); m_ = fmaxf(m_, __shfl_xor(m_, 2)); \
    m_ = fmaxf(m_, __shfl_xor(m_, 4)); m_ = fmaxf(m_, __shfl_xor(m_, 8)); \
    float p_ = __expf(sv - m_); \
    float su_ = p_; \
    su_ += __shfl_xor(su_, 1); su_ += __shfl_xor(su_, 2); \
    su_ += __shfl_xor(su_, 4); su_ += __shfl_xor(su_, 8); \
    aout = p_ / su_; }

#define GRPSUM(x) { x += __shfl_xor(x, 1); x += __shfl_xor(x, 2); \
                    x += __shfl_xor(x, 4); x += __shfl_xor(x, 8); }

__global__ __launch_bounds__(256) void ka_kernel(
    const float* __restrict__ obs,
    const float* __restrict__ bk1, const float* __restrict__ bq1, const float* __restrict__ bv1,
    const float* __restrict__ ws,
    float* __restrict__ out_alpha,
    float* __restrict__ ws_ov)
{
  __shared__ float MT[32 * 36];
  __shared__ float ul[32], rl[32], wvl[32], ccl[2];
  __shared__ float hT[4][96 * HSTR];
  __shared__ float tqT[4][32 * HSTR];
  __shared__ float rql[4][16];

  const int t = threadIdx.x;
  for (int idx = t; idx < 1024; idx += 256) MT[(idx >> 5) * 36 + (idx & 31)] = ws[idx];
  if (t < 32){ ul[t] = ws[1024 + t]; rl[t] = ws[1056 + t]; wvl[t] = ws[1088 + t]; }
  if (t < 2) ccl[t] = ws[1120 + t];
  __syncthreads();

  const int wid = t >> 6, lane = t & 63;
  const int b = blockIdx.x * 4 + wid;
  const int jl = lane & 15;   // node/sender slot within 16-group
  const int gq = lane >> 4;   // 16-lane group id 0..3
  float* hTl  = hT[wid];
  float* tqTl = tqT[wid];

  // ---- A fragments: obs rows -> bf16; lane holds obs[jl][kc*32 + gq*8 + e]
  const float* orow = obs + ((size_t)(b * 16 + jl)) * 128 + gq * 8;
  bf16x8 afr[4];
#pragma unroll
  for (int kc = 0; kc < 4; kc++){
    float4 x0 = *(const float4*)(orow + kc * 32);
    float4 x1 = *(const float4*)(orow + kc * 32 + 4);
    bf16x8 a;
    a[0] = (short)f2bf(x0.x); a[1] = (short)f2bf(x0.y);
    a[2] = (short)f2bf(x0.z); a[3] = (short)f2bf(x0.w);
    a[4] = (short)f2bf(x1.x); a[5] = (short)f2bf(x1.y);
    a[6] = (short)f2bf(x1.z); a[7] = (short)f2bf(x1.w);
    afr[kc] = a;
  }

  const bf16x8* bp = (const bf16x8*)(ws + 1152);
#pragma unroll
  for (int mt = 0; mt < 6; mt++){
    f32x4 c = {0.f, 0.f, 0.f, 0.f};
#pragma unroll
    for (int kc = 0; kc < 4; kc++){
      bf16x8 bfr = bp[(mt * 4 + kc) * 64 + lane];
      c = __builtin_amdgcn_mfma_f32_16x16x32_bf16(afr[kc], bfr, c, 0, 0, 0);
    }
    const int m = mt >> 1;
    const int hcol = ((mt & 1) << 4) + jl;
    const float* bb = (m == 0) ? bk1 : ((m == 1) ? bq1 : bv1);
    const float bias = bb[hcol];
    float4 hv;
    hv.x = fast_tanh(c[0] + bias);
    hv.y = fast_tanh(c[1] + bias);
    hv.z = fast_tanh(c[2] + bias);
    hv.w = fast_tanh(c[3] + bias);
    // store transposed: hT[hid][node], nodes 4*gq..4*gq+3 contiguous -> b128
    *(float4*)(&hTl[(m * 32 + hcol) * HSTR + gq * 4]) = hv;
  }

  // ---- vv[j] = h_v[j,:].wv + cv  (j = jl; redundant across gq groups)
  float vv = ccl[1];
#pragma unroll 8
  for (int h = 0; h < 32; h++) vv += wvl[h] * hTl[(64 + h) * HSTR + jl];

  // ---- tq[i][h] = sum_g M[h][g] hq[i][g];  rq[i] = sum_g r[g] hq[i][g]; i = jl
  float tq0=0,tq1=0,tq2=0,tq3=0,tq4=0,tq5=0,tq6=0,tq7=0, rqv=0;
  const int h8 = gq * 8;
  for (int g = 0; g < 32; g++){
    const float hq = hTl[(32 + g) * HSTR + jl];
    float4 m0 = *(const float4*)(&MT[g * 36 + h8]);
    float4 m1 = *(const float4*)(&MT[g * 36 + h8 + 4]);
    tq0 += m0.x * hq; tq1 += m0.y * hq; tq2 += m0.z * hq; tq3 += m0.w * hq;
    tq4 += m1.x * hq; tq5 += m1.y * hq; tq6 += m1.z * hq; tq7 += m1.w * hq;
    rqv += rl[g] * hq;
  }
  tqTl[(h8 + 0) * HSTR + jl] = tq0;
  tqTl[(h8 + 1) * HSTR + jl] = tq1;
  tqTl[(h8 + 2) * HSTR + jl] = tq2;
  tqTl[(h8 + 3) * HSTR + jl] = tq3;
  tqTl[(h8 + 4) * HSTR + jl] = tq4;
  tqTl[(h8 + 5) * HSTR + jl] = tq5;
  tqTl[(h8 + 6) * HSTR + jl] = tq6;
  tqTl[(h8 + 7) * HSTR + jl] = tq7;
  if (gq == 0) rql[wid][jl] = rqv;

  // ---- scores[i][j]: j = jl, i = 4*gq + r
  float sc0=0,sc1=0,sc2=0,sc3=0, uk=0;
  for (int h = 0; h < 32; h++){
    const float hk = hTl[h * HSTR + jl];
    float4 tqv = *(const float4*)(&tqTl[h * HSTR + gq * 4]);
    sc0 += hk * tqv.x; sc1 += hk * tqv.y; sc2 += hk * tqv.z; sc3 += hk * tqv.w;
    uk += ul[h] * hk;
  }
  const float cc = ccl[0];
  const float rs = 0.08838834764831845f;  // 1/sqrt(128)
  float s0 = (sc0 + uk + rql[wid][gq * 4 + 0] + cc) * rs;
  float s1 = (sc1 + uk + rql[wid][gq * 4 + 1] + cc) * rs;
  float s2 = (sc2 + uk + rql[wid][gq * 4 + 2] + cc) * rs;
  float s3 = (sc3 + uk + rql[wid][gq * 4 + 3] + cc) * rs;

  // ---- softmax over j (lanes within 16-group)
  float a0, a1, a2, a3;
  ROWSOFTMAX(s0, a0); ROWSOFTMAX(s1, a1); ROWSOFTMAX(s2, a2); ROWSOFTMAX(s3, a3);

  float* oa = out_alpha + (size_t)b * 256;
  oa[gq * 64 +  0 + jl] = a0;
  oa[gq * 64 + 16 + jl] = a1;
  oa[gq * 64 + 32 + jl] = a2;
  oa[gq * 64 + 48 + jl] = a3;

  // ---- ov[i] = sum_j alpha[i][j] * vv[j]
  float o0 = a0 * vv; GRPSUM(o0);
  float o1 = a1 * vv; GRPSUM(o1);
  float o2 = a2 * vv; GRPSUM(o2);
  float o3 = a3 * vv; GRPSUM(o3);
  if (jl == 0) ws_ov[b * 16 + gq * 4 + 0] = o0;
  if (jl == 1) ws_ov[b * 16 + gq * 4 + 1] = o1;
  if (jl == 2) ws_ov[b * 16 + gq * 4 + 2] = o2;
  if (jl == 3) ws_ov[b * 16 + gq * 4 + 3] = o3;
}

// ---------------------------------------------------------------------------
// KB: one block per batch; streams noise (the 64MB input) fully coalesced.
// ---------------------------------------------------------------------------
__global__ __launch_bounds__(256) void kb_kernel(
    const float* __restrict__ policies, const float* __restrict__ actions,
    const float* __restrict__ noise, const float* __restrict__ weights,
    const float* __restrict__ Wval, const float* __restrict__ bval,
    const float* __restrict__ ws_ov, float* __restrict__ out)
{
  __shared__ float nv_l[256];
  __shared__ float pv_l[16], av_l[16];
  const int b = blockIdx.x, t = threadIdx.x;
  const float w = weights[0];
  const int q = t & 7;
  const float4 wv4 = *(const float4*)(Wval + 128 + q * 4);

  { // pv/av: 16 threads per node j, 2 action dims each, shfl-reduce over 16
    const int j = t >> 4; const int a0 = (t & 15) * 2;
    const float wa = Wval[128 + a0], wb = Wval[128 + a0 + 1];
    const float* pp = policies + ((size_t)(b * 16 + j)) * 32 + a0;
    const float* ap = actions  + ((size_t)(b * 16 + j)) * 32 + a0;
    float p = pp[0] * wa + pp[1] * wb;
    float a = ap[0] * wa + ap[1] * wb;
    GRPSUM(p); GRPSUM(a);
    if ((t & 15) == 0){ pv_l[j] = p; av_l[j] = a; }
  }
  { // nv[i*16+j] = noise row . Wval2 ; 8 lanes per row -> 1KB/instr coalesced
    const float* nb = noise + (size_t)b * 8192;
#pragma unroll
    for (int k2 = 0; k2 < 8; k2++){
      const int row = k2 * 32 + (t >> 3);
      const float4 n4 = *(const float4*)(nb + row * 32 + q * 4);
      float s = n4.x * wv4.x + n4.y * wv4.y + n4.z * wv4.z + n4.w * wv4.w;
      s += __shfl_xor(s, 1); s += __shfl_xor(s, 2); s += __shfl_xor(s, 4);
      if (q == 0) nv_l[row] = s;
    }
  }
  __syncthreads();
  const int j = t & 15;
  const float pv = pv_l[j], av = av_l[j];
  const float zval = w * av + (1.f - w) * pv + nv_l[t];
  float zs = zval;
  GRPSUM(zs);  // zsum over senders j within the 16-lane group (fixed i)
  out[(size_t)b * 256 + t] = ws_ov[b * 16 + j] + (pv - zval + zs) * 0.0625f + bval[0];
}

// ---------------------------------------------------------------------------
extern "C" void kernel_launch(void* const* d_in, const int* in_sizes, int n_in,
                              void* d_out, int out_size, void* d_ws, size_t ws_size,
                              hipStream_t stream)
{
  const float* obs      = (const float*)d_in[0];
  const float* policies = (const float*)d_in[1];
  const float* actions  = (const float*)d_in[2];
  const float* weights  = (const float*)d_in[3];
  const float* noise    = (const float*)d_in[4];
  const float* Wk1  = (const float*)d_in[5];
  const float* bk1  = (const float*)d_in[6];
  const float* Wk2  = (const float*)d_in[7];
  const float* bk2  = (const float*)d_in[8];
  const float* Wq1  = (const float*)d_in[9];
  const float* bq1  = (const float*)d_in[10];
  const float* Wq2  = (const float*)d_in[11];
  const float* bq2  = (const float*)d_in[12];
  const float* Wv1  = (const float*)d_in[13];
  const float* bv1  = (const float*)d_in[14];
  const float* Wv2  = (const float*)d_in[15];
  const float* bv2  = (const float*)d_in[16];
  const float* Wval = (const float*)d_in[17];
  const float* bval = (const float*)d_in[18];

  float* out = (float*)d_out;
  float* ws  = (float*)d_ws;
  float* ws_ov = ws + 8192;

  const int NODES = in_sizes[0] / 128;
  const int B = NODES / 16;

  hipLaunchKernelGGL(k0_kernel, dim3(64), dim3(64), 0, stream,
                     Wk1, Wq1, Wv1, Wk2, bk2, Wq2, bq2, Wv2, bv2, Wval, ws);
  hipLaunchKernelGGL(ka_kernel, dim3(B / 4), dim3(256), 0, stream,
                     obs, bk1, bq1, bv1, ws, out + (size_t)NODES * 16, ws_ov);
  hipLaunchKernelGGL(kb_kernel, dim3(B), dim3(256), 0, stream,
                     policies, actions, noise, weights, Wval, bval, ws_ov, out);
}